// Round 1
// baseline (6048.286 us; speedup 1.0000x reference)
//
#include <hip/hip_runtime.h>

#define BS 256
#define IN_LEN 512
#define T_OUT 64
#define H 1024
#define G4 4096

__device__ __forceinline__ float sigf(float x) {
    return 1.f / (1.f + __expf(-x));
}
__device__ __forceinline__ float tanhfast(float x) {
    // 1 - 2/(e^{2x}+1); saturates correctly at +/-1 via inf/0
    return 1.f - 2.f / (__expf(2.f * x) + 1.f);
}

// ---------------- h0 = einsum("bih,i->bh", qf, w_in) + b_in ; c = 0 -------------
__global__ __launch_bounds__(256) void k_h0(const float4* __restrict__ qf4,
                                            const float* __restrict__ w_in,
                                            const float* __restrict__ b_in,
                                            float4* __restrict__ h4,
                                            float4* __restrict__ c4) {
    int idx = blockIdx.x * blockDim.x + threadIdx.x;   // 0 .. BS*H/4-1
    int b = idx >> 8;                                  // H/4 = 256
    int hi = idx & 255;
    const float4* p = qf4 + (size_t)b * IN_LEN * (H / 4) + hi;
    float4 s = make_float4(0.f, 0.f, 0.f, 0.f);
#pragma unroll 4
    for (int i = 0; i < IN_LEN; ++i) {
        float w = w_in[i];
        float4 q = p[(size_t)i * (H / 4)];
        s.x += q.x * w; s.y += q.y * w; s.z += q.z * w; s.w += q.w * w;
    }
    float bi = b_in[0];
    s.x += bi; s.y += bi; s.z += bi; s.w += bi;
    h4[idx] = s;
    c4[idx] = make_float4(0.f, 0.f, 0.f, 0.f);
}

// ---------------- Wc = w_ih + w_hh ; bc = b_ih + b_hh ---------------------------
__global__ __launch_bounds__(256) void k_prep(const float4* __restrict__ w_ih,
                                              const float4* __restrict__ w_hh,
                                              const float4* __restrict__ b_ih,
                                              const float4* __restrict__ b_hh,
                                              float4* __restrict__ Wc,
                                              float4* __restrict__ bc) {
    int i = blockIdx.x * blockDim.x + threadIdx.x;     // 0 .. 4096*1024/4-1
    float4 a = w_ih[i], b = w_hh[i];
    Wc[i] = make_float4(a.x + b.x, a.y + b.y, a.z + b.z, a.w + b.w);
    if (i < G4 / 4) {
        float4 x = b_ih[i], y = b_hh[i];
        bc[i] = make_float4(x.x + y.x, x.y + y.y, x.z + y.z, x.w + y.w);
    }
}

// ---------------- g0[j] = dot(start_token, w_ih[j,:]) + b_ih[j] + b_hh[j] -------
__global__ __launch_bounds__(256) void k_g0(const float* __restrict__ st,
                                            const float* __restrict__ w_ih,
                                            const float* __restrict__ b_ih,
                                            const float* __restrict__ b_hh,
                                            float* __restrict__ g0) {
    int j = (blockIdx.x * blockDim.x + threadIdx.x) >> 6;  // wave id = gate row
    int lane = threadIdx.x & 63;
    const float4* wr = (const float4*)(w_ih + (size_t)j * H);
    const float4* st4 = (const float4*)st;
    float s = 0.f;
#pragma unroll
    for (int q = 0; q < 4; ++q) {
        int idx = q * 64 + lane;
        float4 w4 = wr[idx];
        float4 s4 = st4[idx];
        s += w4.x * s4.x + w4.y * s4.y + w4.z * s4.z + w4.w * s4.w;
    }
#pragma unroll
    for (int off = 32; off > 0; off >>= 1) s += __shfl_down(s, off, 64);
    if (lane == 0) g0[j] = s + b_ih[j] + b_hh[j];
}

// ---------------- fused LSTM step: gates = h_in @ W^T + bias, then cell ---------
// grid (H/32, BS/32) = (32, 8); block 256.
// Tile: 32 batch x 32 hh x 4 gates. Each thread: 2b x 2hh x 4g = 16 accumulators.
// LDS double-buffered (register prefetch of next K-chunk during compute).
#define KB 32
__global__ __launch_bounds__(256) void k_step(const float* __restrict__ W,    // [4096][1024]
                                              const float* __restrict__ bias, // [4096]
                                              const float* __restrict__ h_in, // [256][1024]
                                              float* __restrict__ c,          // [256][1024]
                                              float* __restrict__ h_next,     // [256][1024]
                                              float* __restrict__ out_h,      // d_out+1048576
                                              int t) {
    __shared__ float sA[2][32][36];    // pad 36: float4-aligned rows, 2-way banks only
    __shared__ float sW[2][128][36];

    const int tid = threadIdx.x;
    const int h0 = blockIdx.x * 32;
    const int b0 = blockIdx.y * 32;
    const int tx = tid & 15, ty = tid >> 4;

    // staging addresses
    const int ar = tid >> 3, ac = (tid & 7) * 4;       // sA: row 0..31, col4
    const float* gA = h_in + (size_t)(b0 + ar) * H + ac;
    const float* gW[4];
    int wr_[4], wc_[4];
#pragma unroll
    for (int q = 0; q < 4; ++q) {
        int j = tid * 4 + q;                           // 0..1023 float4 slots
        int wr = j >> 3, wc = (j & 7) * 4;             // wr 0..127
        wr_[q] = wr; wc_[q] = wc;
        int gate = wr >> 5, hl = wr & 31;
        gW[q] = W + ((size_t)gate * H + h0 + hl) * H + wc;
    }

    // prefetch chunk 0 into buffer 0
    float4 ra = *(const float4*)gA;
    float4 rw[4];
#pragma unroll
    for (int q = 0; q < 4; ++q) rw[q] = *(const float4*)gW[q];
    *(float4*)&sA[0][ar][ac] = ra;
#pragma unroll
    for (int q = 0; q < 4; ++q) *(float4*)&sW[0][wr_[q]][wc_[q]] = rw[q];
    __syncthreads();

    float acc[4][4];
#pragma unroll
    for (int g = 0; g < 4; ++g)
#pragma unroll
        for (int i = 0; i < 4; ++i) acc[g][i] = 0.f;

#pragma unroll 1
    for (int ch = 0; ch < H / KB; ++ch) {
        const int cur = ch & 1;
        if (ch < H / KB - 1) {                         // prefetch next chunk
            int k0 = (ch + 1) * KB;
            ra = *(const float4*)(gA + k0);
#pragma unroll
            for (int q = 0; q < 4; ++q) rw[q] = *(const float4*)(gW[q] + k0);
        }
#pragma unroll
        for (int kk = 0; kk < KB; ++kk) {
            float a0 = sA[cur][ty][kk];
            float a1 = sA[cur][ty + 16][kk];
#pragma unroll
            for (int g = 0; g < 4; ++g) {
                float w0 = sW[cur][g * 32 + tx][kk];
                float w1 = sW[cur][g * 32 + tx + 16][kk];
                acc[g][0] += a0 * w0;
                acc[g][1] += a0 * w1;
                acc[g][2] += a1 * w0;
                acc[g][3] += a1 * w1;
            }
        }
        if (ch < H / KB - 1) {
            const int nxt = cur ^ 1;
            *(float4*)&sA[nxt][ar][ac] = ra;
#pragma unroll
            for (int q = 0; q < 4; ++q) *(float4*)&sW[nxt][wr_[q]][wc_[q]] = rw[q];
        }
        __syncthreads();
    }

    // LSTM cell epilogue
#pragma unroll
    for (int bi = 0; bi < 2; ++bi) {
        int b = b0 + ty + bi * 16;
#pragma unroll
        for (int hi = 0; hi < 2; ++hi) {
            int hh = h0 + tx + hi * 16;
            int i = bi * 2 + hi;
            float ig = acc[0][i] + bias[hh];
            float fg = acc[1][i] + bias[H + hh];
            float gg = acc[2][i] + bias[2 * H + hh];
            float og = acc[3][i] + bias[3 * H + hh];
            float cold = c[(size_t)b * H + hh];
            float cn = sigf(fg) * cold + sigf(ig) * tanhfast(gg);
            float hn = sigf(og) * tanhfast(cn);
            c[(size_t)b * H + hh] = cn;
            h_next[(size_t)b * H + hh] = hn;
            out_h[((size_t)b * T_OUT + t) * H + hh] = hn;
        }
    }
}

// ---------------- probs = hs @ w_out^T + b_out ----------------------------------
// M=BS*T_OUT=16384 rows, N=64, K=1024. Tile 64 rows x 64 cols, block 256.
__global__ __launch_bounds__(256) void k_probs(const float* __restrict__ hs,    // [16384][1024]
                                               const float* __restrict__ w_out, // [64][1024]
                                               const float* __restrict__ b_out, // [64]
                                               float* __restrict__ probs) {     // [16384][64]
    __shared__ float sX[64][36];
    __shared__ float sWo[64][36];
    const int r0 = blockIdx.x * 64;
    const int tid = threadIdx.x;
    const int tx = tid & 15, ty = tid >> 4;
    float acc[4][4];
#pragma unroll
    for (int i = 0; i < 4; ++i)
#pragma unroll
        for (int j = 0; j < 4; ++j) acc[i][j] = 0.f;

    for (int k0 = 0; k0 < H; k0 += 32) {
#pragma unroll
        for (int q = 0; q < 2; ++q) {
            int j = tid + q * 256;                     // 0..511
            int rr = j >> 3, cc = (j & 7) * 4;
            *(float4*)&sX[rr][cc] = *(const float4*)&hs[(size_t)(r0 + rr) * H + k0 + cc];
            *(float4*)&sWo[rr][cc] = *(const float4*)&w_out[(size_t)rr * H + k0 + cc];
        }
        __syncthreads();
#pragma unroll
        for (int kk = 0; kk < 32; ++kk) {
            float x[4], w[4];
#pragma unroll
            for (int i = 0; i < 4; ++i) x[i] = sX[ty + 16 * i][kk];
#pragma unroll
            for (int i = 0; i < 4; ++i) w[i] = sWo[tx + 16 * i][kk];
#pragma unroll
            for (int i = 0; i < 4; ++i)
#pragma unroll
                for (int j = 0; j < 4; ++j) acc[i][j] += x[i] * w[j];
        }
        __syncthreads();
    }
#pragma unroll
    for (int i = 0; i < 4; ++i) {
        int row = r0 + ty + 16 * i;
#pragma unroll
        for (int j = 0; j < 4; ++j) {
            int o = tx + 16 * j;
            probs[(size_t)row * 64 + o] = acc[i][j] + b_out[o];
        }
    }
}

extern "C" void kernel_launch(void* const* d_in, const int* in_sizes, int n_in,
                              void* d_out, int out_size, void* d_ws, size_t ws_size,
                              hipStream_t stream) {
    const float* qf    = (const float*)d_in[1];
    const float* st    = (const float*)d_in[4];
    const float* w_in  = (const float*)d_in[5];
    const float* b_in  = (const float*)d_in[6];
    const float* w_ih  = (const float*)d_in[7];
    const float* w_hh  = (const float*)d_in[8];
    const float* b_ih  = (const float*)d_in[9];
    const float* b_hh  = (const float*)d_in[10];
    const float* w_out = (const float*)d_in[11];
    const float* b_out = (const float*)d_in[12];

    float* probs = (float*)d_out;                  // [256*64*64]
    float* out_h = probs + (size_t)BS * T_OUT * 64; // [256*64*1024]

    // workspace layout (floats): Wc 4194304 | bc 4096 | g0 4096 | h0 262144 | h1 262144 | c 262144
    float* Wc  = (float*)d_ws;
    float* bc  = Wc + (size_t)G4 * H;
    float* g0  = bc + G4;
    float* h0b = g0 + G4;
    float* h1b = h0b + (size_t)BS * H;
    float* cb  = h1b + (size_t)BS * H;

    k_prep<<<dim3((G4 * H / 4) / 256), 256, 0, stream>>>(
        (const float4*)w_ih, (const float4*)w_hh, (const float4*)b_ih,
        (const float4*)b_hh, (float4*)Wc, (float4*)bc);
    k_g0<<<dim3(G4 / 4), 256, 0, stream>>>(st, w_ih, b_ih, b_hh, g0);
    k_h0<<<dim3((BS * H / 4) / 256), 256, 0, stream>>>(
        (const float4*)qf, w_in, b_in, (float4*)h0b, (float4*)cb);

    for (int t = 0; t < T_OUT; ++t) {
        const float* Wt  = (t == 0) ? w_hh : Wc;
        const float* bt  = (t == 0) ? g0 : bc;
        const float* hin = (t & 1) ? h1b : h0b;
        float* hout      = (t & 1) ? h0b : h1b;
        k_step<<<dim3(H / 32, BS / 32), 256, 0, stream>>>(Wt, bt, hin, cb, hout, out_h, t);
    }
    k_probs<<<dim3(BS * T_OUT / 64), 256, 0, stream>>>(out_h, w_out, b_out, probs);
}

// Round 2
// 2173.352 us; speedup vs baseline: 2.7829x; 2.7829x over previous
//
#include <hip/hip_runtime.h>

#define BS 256
#define IN_LEN 512
#define T_OUT 64
#define H 1024
#define G4 4096

typedef __attribute__((ext_vector_type(8))) short bf16x8;
typedef __attribute__((ext_vector_type(4))) float f32x4;

__device__ __forceinline__ unsigned short f2bf(float x) {
    union { float f; unsigned u; } v; v.f = x;
    unsigned r = v.u + 0x7fffu + ((v.u >> 16) & 1u);   // RTNE
    return (unsigned short)(r >> 16);
}
__device__ __forceinline__ float bf2f(unsigned short b) {
    union { unsigned u; float f; } v; v.u = ((unsigned)b) << 16;
    return v.f;
}
__device__ __forceinline__ float sigf(float x) { return 1.f / (1.f + __expf(-x)); }
__device__ __forceinline__ float tanhfast(float x) { return 1.f - 2.f / (__expf(2.f * x) + 1.f); }

__device__ __forceinline__ void gl_lds16(const void* g, void* l) {
    __builtin_amdgcn_global_load_lds((const __attribute__((address_space(1))) void*)g,
                                     (__attribute__((address_space(3))) void*)l, 16, 0, 0);
}

// ---- pack Wc = w_ih + w_hh into bf16 hi/lo, rows permuted p = hh*4+gate; also split w_out
__global__ __launch_bounds__(256) void k_prep(const float4* __restrict__ w_ih4,
                                              const float4* __restrict__ w_hh4,
                                              const float4* __restrict__ w_out4,
                                              ushort4* __restrict__ Wch, ushort4* __restrict__ Wcl,
                                              ushort4* __restrict__ woh, ushort4* __restrict__ wol) {
    int row = blockIdx.x;        // source row 0..4095 (gate-major)
    int c4 = threadIdx.x;        // 0..255 float4 cols
    float4 a = w_ih4[row * 256 + c4];
    float4 b = w_hh4[row * 256 + c4];
    int p = ((row & 1023) << 2) | (row >> 10);   // packed row hh*4+gate
    float sx = a.x + b.x, sy = a.y + b.y, sz = a.z + b.z, sw = a.w + b.w;
    ushort4 hi, lo;
    hi.x = f2bf(sx); lo.x = f2bf(sx - bf2f(hi.x));
    hi.y = f2bf(sy); lo.y = f2bf(sy - bf2f(hi.y));
    hi.z = f2bf(sz); lo.z = f2bf(sz - bf2f(hi.z));
    hi.w = f2bf(sw); lo.w = f2bf(sw - bf2f(hi.w));
    Wch[p * 256 + c4] = hi;
    Wcl[p * 256 + c4] = lo;
    if (row < 64) {
        float4 w = w_out4[row * 256 + c4];
        ushort4 h2, l2;
        h2.x = f2bf(w.x); l2.x = f2bf(w.x - bf2f(h2.x));
        h2.y = f2bf(w.y); l2.y = f2bf(w.y - bf2f(h2.y));
        h2.z = f2bf(w.z); l2.z = f2bf(w.z - bf2f(h2.z));
        h2.w = f2bf(w.w); l2.w = f2bf(w.w - bf2f(h2.w));
        woh[row * 256 + c4] = h2;
        wol[row * 256 + c4] = l2;
    }
}

// ---- g0p[p] = dot(start_token, w_ih[row]) + b_ih + b_hh (packed); bcp[p] = b_ih+b_hh
__global__ __launch_bounds__(256) void k_g0(const float4* __restrict__ st4,
                                            const float4* __restrict__ w_ih4,
                                            const float* __restrict__ b_ih,
                                            const float* __restrict__ b_hh,
                                            float* __restrict__ g0p, float* __restrict__ bcp) {
    int j = (blockIdx.x * 256 + threadIdx.x) >> 6;   // source row 0..4095
    int lane = threadIdx.x & 63;
    float s = 0.f;
#pragma unroll
    for (int q = 0; q < 4; ++q) {
        int idx = q * 64 + lane;
        float4 w4 = w_ih4[(size_t)j * 256 + idx];
        float4 s4 = st4[idx];
        s += w4.x * s4.x + w4.y * s4.y + w4.z * s4.z + w4.w * s4.w;
    }
#pragma unroll
    for (int off = 32; off > 0; off >>= 1) s += __shfl_down(s, off, 64);
    if (lane == 0) {
        int p = ((j & 1023) << 2) | (j >> 10);
        float bb = b_ih[j] + b_hh[j];
        bcp[p] = bb;
        g0p[p] = s + bb;
    }
}

// ---- h0 = einsum("bih,i->bh") + b_in, split to bf16 hi/lo; c = 0
__global__ __launch_bounds__(256) void k_h0(const float4* __restrict__ qf4,
                                            const float* __restrict__ w_in,
                                            const float* __restrict__ b_in,
                                            ushort4* __restrict__ h_hi, ushort4* __restrict__ h_lo,
                                            float4* __restrict__ c4) {
    int idx = blockIdx.x * 256 + threadIdx.x;  // 0..65535; b = idx>>8, hq = idx&255
    int b = idx >> 8;
    int hq = idx & 255;
    const float4* p = qf4 + (size_t)b * IN_LEN * 256 + hq;
    float4 s = make_float4(0.f, 0.f, 0.f, 0.f);
#pragma unroll 4
    for (int i = 0; i < IN_LEN; ++i) {
        float w = w_in[i];
        float4 q = p[(size_t)i * 256];
        s.x += q.x * w; s.y += q.y * w; s.z += q.z * w; s.w += q.w * w;
    }
    float bi = b_in[0];
    s.x += bi; s.y += bi; s.z += bi; s.w += bi;
    ushort4 hi, lo;
    hi.x = f2bf(s.x); lo.x = f2bf(s.x - bf2f(hi.x));
    hi.y = f2bf(s.y); lo.y = f2bf(s.y - bf2f(hi.y));
    hi.z = f2bf(s.z); lo.z = f2bf(s.z - bf2f(hi.z));
    hi.w = f2bf(s.w); lo.w = f2bf(s.w - bf2f(hi.w));
    h_hi[idx] = hi;
    h_lo[idx] = lo;
    c4[idx] = make_float4(0.f, 0.f, 0.f, 0.f);
}

// ---- fused LSTM step: gates = h @ W^T (split-bf16 MFMA) + bias, then cell
// grid (64, 4): blockIdx.x = packed-col tile (64 cols = 16 hh x 4 gates), blockIdx.y = batch tile (64)
__global__ __launch_bounds__(256) void k_step(const ushort* __restrict__ Bh,  // packed Wc hi
                                              const ushort* __restrict__ Bl,  // packed Wc lo
                                              const float* __restrict__ Bf,   // w_hh fp32 (t==0 path)
                                              const float* __restrict__ bias, // packed [4096]
                                              const ushort* __restrict__ Ah,  // h_in hi [256][1024]
                                              const ushort* __restrict__ Al,  // h_in lo
                                              float* __restrict__ c,
                                              ushort* __restrict__ Oh, ushort* __restrict__ Ol,
                                              float* __restrict__ out_h, int t, int useF32) {
    __shared__ __align__(16) ushort sAh[64 * 32], sAl[64 * 32], sBh[64 * 32], sBl[64 * 32];
    __shared__ __align__(16) float sC[64 * 68];

    const int tid = threadIdx.x;
    const int n0 = blockIdx.x * 64;      // packed col base (hh0 = n0/4)
    const int m0 = blockIdx.y * 64;      // batch base
    const int w = tid >> 6, l = tid & 63;
    const int wm = w & 1, wn = w >> 1;
    const int lm = l & 15, kg = l >> 4;

    const int srow = tid >> 2;           // staging row 0..63
    const int scol = (tid & 3) * 8;      // staging k offset (elems)
    const int ldsOff = (tid >> 6) * 512; // wave-uniform LDS base (ushorts)

    const ushort* gAh = Ah + (m0 + srow) * H + scol;
    const ushort* gAl = Al + (m0 + srow) * H + scol;
    const int prow = n0 + srow;
    const ushort* gBh = Bh + prow * H + scol;
    const ushort* gBl = Bl + prow * H + scol;
    const float* gBf = Bf + ((prow & 3) * H + (prow >> 2)) * H + scol;  // unpack: row = gate*H + hh

    f32x4 acc[2][2];
#pragma unroll
    for (int mi = 0; mi < 2; ++mi)
#pragma unroll
        for (int ni = 0; ni < 2; ++ni) acc[mi][ni] = (f32x4)(0.f);

#pragma unroll 1
    for (int ch = 0; ch < H / 32; ++ch) {
        const int k0 = ch * 32;
        __syncthreads();                  // prior chunk's frag reads done
        if (useF32) {
            float4 f0 = *(const float4*)(gBf + k0);
            float4 f1 = *(const float4*)(gBf + k0 + 4);
            ushort4 h0_, h1_, l0_, l1_;
            h0_.x = f2bf(f0.x); l0_.x = f2bf(f0.x - bf2f(h0_.x));
            h0_.y = f2bf(f0.y); l0_.y = f2bf(f0.y - bf2f(h0_.y));
            h0_.z = f2bf(f0.z); l0_.z = f2bf(f0.z - bf2f(h0_.z));
            h0_.w = f2bf(f0.w); l0_.w = f2bf(f0.w - bf2f(h0_.w));
            h1_.x = f2bf(f1.x); l1_.x = f2bf(f1.x - bf2f(h1_.x));
            h1_.y = f2bf(f1.y); l1_.y = f2bf(f1.y - bf2f(h1_.y));
            h1_.z = f2bf(f1.z); l1_.z = f2bf(f1.z - bf2f(h1_.z));
            h1_.w = f2bf(f1.w); l1_.w = f2bf(f1.w - bf2f(h1_.w));
            int si = srow * 32 + (tid & 3) * 8;
            *(ushort4*)&sBh[si] = h0_; *(ushort4*)&sBh[si + 4] = h1_;
            *(ushort4*)&sBl[si] = l0_; *(ushort4*)&sBl[si + 4] = l1_;
        } else {
            gl_lds16(gBh + k0, &sBh[ldsOff]);
            gl_lds16(gBl + k0, &sBl[ldsOff]);
        }
        gl_lds16(gAh + k0, &sAh[ldsOff]);
        gl_lds16(gAl + k0, &sAl[ldsOff]);
        __syncthreads();                  // staged data visible

        bf16x8 ah[2], al[2], bh[2], bl[2];
#pragma unroll
        for (int mi = 0; mi < 2; ++mi) {
            int base = (wm * 32 + mi * 16 + lm) * 32 + kg * 8;
            ah[mi] = *(const bf16x8*)&sAh[base];
            al[mi] = *(const bf16x8*)&sAl[base];
        }
#pragma unroll
        for (int ni = 0; ni < 2; ++ni) {
            int base = (wn * 32 + ni * 16 + lm) * 32 + kg * 8;
            bh[ni] = *(const bf16x8*)&sBh[base];
            bl[ni] = *(const bf16x8*)&sBl[base];
        }
#pragma unroll
        for (int mi = 0; mi < 2; ++mi)
#pragma unroll
            for (int ni = 0; ni < 2; ++ni) {
                acc[mi][ni] = __builtin_amdgcn_mfma_f32_16x16x32_bf16(ah[mi], bh[ni], acc[mi][ni], 0, 0, 0);
                acc[mi][ni] = __builtin_amdgcn_mfma_f32_16x16x32_bf16(ah[mi], bl[ni], acc[mi][ni], 0, 0, 0);
                acc[mi][ni] = __builtin_amdgcn_mfma_f32_16x16x32_bf16(al[mi], bh[ni], acc[mi][ni], 0, 0, 0);
            }
    }

    // spill C tile to LDS so each thread can gather its (i,f,g,o) quadruple
#pragma unroll
    for (int mi = 0; mi < 2; ++mi)
#pragma unroll
        for (int ni = 0; ni < 2; ++ni) {
            int r0 = wm * 32 + mi * 16 + kg * 4;
            int c0_ = wn * 32 + ni * 16 + lm;
#pragma unroll
            for (int r = 0; r < 4; ++r) sC[(r0 + r) * 68 + c0_] = acc[mi][ni][r];
        }
    __syncthreads();

#pragma unroll
    for (int q = 0; q < 4; ++q) {
        int cid = tid + q * 256;
        int bl_ = cid >> 4, hl = cid & 15;
        float4 gv = *(const float4*)&sC[bl_ * 68 + hl * 4];   // i,f,g,o
        float4 bv = *(const float4*)&bias[n0 + hl * 4];
        int b = m0 + bl_;
        int hh = (n0 >> 2) + hl;
        float cold = c[b * H + hh];
        float ig = gv.x + bv.x, fg = gv.y + bv.y, gg = gv.z + bv.z, og = gv.w + bv.w;
        float cn = sigf(fg) * cold + sigf(ig) * tanhfast(gg);
        float hn = sigf(og) * tanhfast(cn);
        c[b * H + hh] = cn;
        unsigned short hb = f2bf(hn);
        Oh[b * H + hh] = hb;
        Ol[b * H + hh] = f2bf(hn - bf2f(hb));
        out_h[(b * T_OUT + t) * H + hh] = hn;
    }
}

// ---- probs = hs @ w_out^T + b_out  (split-bf16 MFMA; A staged via VALU split from fp32 hs)
__global__ __launch_bounds__(256) void k_probs(const float* __restrict__ hs,   // [16384][1024]
                                               const ushort* __restrict__ Bh,  // wo hi [64][1024]
                                               const ushort* __restrict__ Bl,
                                               const float* __restrict__ b_out,
                                               float* __restrict__ probs) {
    __shared__ __align__(16) ushort sAh[64 * 32], sAl[64 * 32], sBh[64 * 32], sBl[64 * 32];
    const int tid = threadIdx.x;
    const int r0 = blockIdx.x * 64;
    const int w = tid >> 6, l = tid & 63;
    const int wm = w & 1, wn = w >> 1;
    const int lm = l & 15, kg = l >> 4;
    const int srow = tid >> 2;
    const int scol = (tid & 3) * 8;
    const int ldsOff = (tid >> 6) * 512;

    const float* gA = hs + (size_t)(r0 + srow) * H + scol;
    const ushort* gBh = Bh + srow * H + scol;
    const ushort* gBl = Bl + srow * H + scol;

    f32x4 acc[2][2];
#pragma unroll
    for (int mi = 0; mi < 2; ++mi)
#pragma unroll
        for (int ni = 0; ni < 2; ++ni) acc[mi][ni] = (f32x4)(0.f);

#pragma unroll 1
    for (int ch = 0; ch < H / 32; ++ch) {
        const int k0 = ch * 32;
        __syncthreads();
        gl_lds16(gBh + k0, &sBh[ldsOff]);
        gl_lds16(gBl + k0, &sBl[ldsOff]);
        float4 f0 = *(const float4*)(gA + k0);
        float4 f1 = *(const float4*)(gA + k0 + 4);
        ushort4 h0_, h1_, l0_, l1_;
        h0_.x = f2bf(f0.x); l0_.x = f2bf(f0.x - bf2f(h0_.x));
        h0_.y = f2bf(f0.y); l0_.y = f2bf(f0.y - bf2f(h0_.y));
        h0_.z = f2bf(f0.z); l0_.z = f2bf(f0.z - bf2f(h0_.z));
        h0_.w = f2bf(f0.w); l0_.w = f2bf(f0.w - bf2f(h0_.w));
        h1_.x = f2bf(f1.x); l1_.x = f2bf(f1.x - bf2f(h1_.x));
        h1_.y = f2bf(f1.y); l1_.y = f2bf(f1.y - bf2f(h1_.y));
        h1_.z = f2bf(f1.z); l1_.z = f2bf(f1.z - bf2f(h1_.z));
        h1_.w = f2bf(f1.w); l1_.w = f2bf(f1.w - bf2f(h1_.w));
        int si = srow * 32 + (tid & 3) * 8;
        *(ushort4*)&sAh[si] = h0_; *(ushort4*)&sAh[si + 4] = h1_;
        *(ushort4*)&sAl[si] = l0_; *(ushort4*)&sAl[si + 4] = l1_;
        __syncthreads();

        bf16x8 ah[2], al[2], bh[2], bl[2];
#pragma unroll
        for (int mi = 0; mi < 2; ++mi) {
            int base = (wm * 32 + mi * 16 + lm) * 32 + kg * 8;
            ah[mi] = *(const bf16x8*)&sAh[base];
            al[mi] = *(const bf16x8*)&sAl[base];
        }
#pragma unroll
        for (int ni = 0; ni < 2; ++ni) {
            int base = (wn * 32 + ni * 16 + lm) * 32 + kg * 8;
            bh[ni] = *(const bf16x8*)&sBh[base];
            bl[ni] = *(const bf16x8*)&sBl[base];
        }
#pragma unroll
        for (int mi = 0; mi < 2; ++mi)
#pragma unroll
            for (int ni = 0; ni < 2; ++ni) {
                acc[mi][ni] = __builtin_amdgcn_mfma_f32_16x16x32_bf16(ah[mi], bh[ni], acc[mi][ni], 0, 0, 0);
                acc[mi][ni] = __builtin_amdgcn_mfma_f32_16x16x32_bf16(ah[mi], bl[ni], acc[mi][ni], 0, 0, 0);
                acc[mi][ni] = __builtin_amdgcn_mfma_f32_16x16x32_bf16(al[mi], bh[ni], acc[mi][ni], 0, 0, 0);
            }
    }

#pragma unroll
    for (int mi = 0; mi < 2; ++mi)
#pragma unroll
        for (int ni = 0; ni < 2; ++ni) {
            int col = wn * 32 + ni * 16 + lm;
            float bo = b_out[col];
            int rowb = r0 + wm * 32 + mi * 16 + kg * 4;
#pragma unroll
            for (int r = 0; r < 4; ++r)
                probs[(size_t)(rowb + r) * 64 + col] = acc[mi][ni][r] + bo;
        }
}

extern "C" void kernel_launch(void* const* d_in, const int* in_sizes, int n_in,
                              void* d_out, int out_size, void* d_ws, size_t ws_size,
                              hipStream_t stream) {
    const float* qf    = (const float*)d_in[1];
    const float* st    = (const float*)d_in[4];
    const float* w_in  = (const float*)d_in[5];
    const float* b_in  = (const float*)d_in[6];
    const float* w_ih  = (const float*)d_in[7];
    const float* w_hh  = (const float*)d_in[8];
    const float* b_ih  = (const float*)d_in[9];
    const float* b_hh  = (const float*)d_in[10];
    const float* w_out = (const float*)d_in[11];
    const float* b_out = (const float*)d_in[12];

    float* probs = (float*)d_out;                        // [256][64][64]
    float* out_h = probs + (size_t)BS * T_OUT * 64;      // [256][64][1024]

    char* ws = (char*)d_ws;
    ushort* Wch = (ushort*)ws; ws += (size_t)G4 * H * 2;   // 8 MB
    ushort* Wcl = (ushort*)ws; ws += (size_t)G4 * H * 2;
    ushort* woh = (ushort*)ws; ws += (size_t)64 * H * 2;
    ushort* wol = (ushort*)ws; ws += (size_t)64 * H * 2;
    float*  bcp = (float*)ws;  ws += G4 * 4;
    float*  g0p = (float*)ws;  ws += G4 * 4;
    ushort* hAh = (ushort*)ws; ws += (size_t)BS * H * 2;
    ushort* hAl = (ushort*)ws; ws += (size_t)BS * H * 2;
    ushort* hBh = (ushort*)ws; ws += (size_t)BS * H * 2;
    ushort* hBl = (ushort*)ws; ws += (size_t)BS * H * 2;
    float*  cb  = (float*)ws;  ws += (size_t)BS * H * 4;

    k_prep<<<G4, 256, 0, stream>>>((const float4*)w_ih, (const float4*)w_hh, (const float4*)w_out,
                                   (ushort4*)Wch, (ushort4*)Wcl, (ushort4*)woh, (ushort4*)wol);
    k_g0<<<G4 / 4, 256, 0, stream>>>((const float4*)st, (const float4*)w_ih, b_ih, b_hh, g0p, bcp);
    k_h0<<<BS * H / 4 / 256, 256, 0, stream>>>((const float4*)qf, w_in, b_in,
                                               (ushort4*)hAh, (ushort4*)hAl, (float4*)cb);

    for (int t = 0; t < T_OUT; ++t) {
        const ushort* Ah = (t & 1) ? hBh : hAh;
        const ushort* Al = (t & 1) ? hBl : hAl;
        ushort* Oh = (t & 1) ? hAh : hBh;
        ushort* Ol = (t & 1) ? hAl : hBl;
        k_step<<<dim3(64, 4), 256, 0, stream>>>(Wch, Wcl, w_hh,
                                                (t == 0) ? g0p : bcp,
                                                Ah, Al, cb, Oh, Ol, out_h, t, (t == 0) ? 1 : 0);
    }
    k_probs<<<BS * T_OUT / 64, 256, 0, stream>>>(out_h, woh, wol, b_out, probs);
}